// Round 3
// baseline (497.708 us; speedup 1.0000x reference)
//
#include <hip/hip_runtime.h>
#include <hip/hip_bf16.h>
#include <cstdint>

// Problem constants
constexpr int B_   = 64;
constexpr int L_   = 512;
constexpr int G_   = 128;
constexpr int E_   = 65536;
constexpr int DTOK = 64;
constexpr int RH   = 256;    // NREL*NHID
constexpr int M_   = 2048;   // B*N distinct nodes
constexpr int JA   = 33;     // augmented j (32 + const-1 slot)
constexpr int COLS = RH * JA;   // 8448
constexpr int STRD = 36;        // padded row stride for hs/ht (float4-friendly)
constexpr int K_   = 8;

#define DEV static __device__ __forceinline__

DEV float sigm(float x) { return 1.f / (1.f + __expf(-x)); }
DEV float tanh_fast(float x) {
    x = fminf(15.f, fmaxf(-15.f, x));
    float e = __expf(2.f * x);
    return (e - 1.f) / (e + 1.f);
}
DEV int rfl(int x) { return __builtin_amdgcn_readfirstlane(x); }

// ---------------- K_eh: embed (LDS-atomic scatter) + edge histograms --------
__global__ __launch_bounds__(256) void k_eh(const int* __restrict__ seq,
                                            const int* __restrict__ p2g,
                                            const float* __restrict__ emb,
                                            const int* __restrict__ u,
                                            const int* __restrict__ v,
                                            float* __restrict__ xg,
                                            int* __restrict__ cu, int* __restrict__ cv) {
    int blk = blockIdx.x;
    int t   = threadIdx.x;
    if (blk >= 64) {
        int n = (blk - 64) * 256 + t;
        atomicAdd(&cu[u[n]], 1);
        atomicAdd(&cv[v[n]], 1);
        return;
    }
    __shared__ float xgl[G_ * 64];          // 32 KB
    for (int i = t; i < G_ * 64; i += 256) xgl[i] = 0.f;
    __syncthreads();
    int b = blk;
    int d = t & 63, part = t >> 6;
#pragma unroll 4
    for (int l = part; l < L_; l += 4) {     // l uniform per wave -> scalar loads
        int s = seq[b * L_ + l];
        int g = p2g[b * L_ + l];
        atomicAdd(&xgl[g * 64 + d], emb[s * 64 + d]);
    }
    __syncthreads();
    for (int i = t; i < G_ * 64; i += 256) xg[(size_t)b * G_ * 64 + i] = xgl[i];
}

// ---------------- K_pre: input-gate GEMM (scalar x broadcast) + scan --------
__global__ __launch_bounds__(256) void k_pre(const float* __restrict__ xg,
                                             const float* __restrict__ wihf,
                                             const float* __restrict__ bihf,
                                             const float* __restrict__ bhhf,
                                             const float* __restrict__ wihb,
                                             const float* __restrict__ bihb,
                                             const float* __restrict__ bhhb,
                                             float* __restrict__ pre,
                                             const int* __restrict__ cu,
                                             int* __restrict__ ustart,
                                             int* __restrict__ ucursor) {
    int blk = blockIdx.x;
    int t   = threadIdx.x;
    if (blk == 512) {
        __shared__ int ps[256];
        int base = t * 8, run = 0;
        int c[8], loc[8];
#pragma unroll
        for (int i = 0; i < 8; i++) c[i] = cu[base + i];
#pragma unroll
        for (int i = 0; i < 8; i++) { loc[i] = run; run += c[i]; }
        ps[t] = run;
        __syncthreads();
        for (int off = 1; off < 256; off <<= 1) {
            int a = (t >= off) ? ps[t - off] : 0;
            __syncthreads();
            ps[t] += a;
            __syncthreads();
        }
        int ex = ps[t] - run;
#pragma unroll
        for (int i = 0; i < 8; i++) { ustart[base + i] = ex + loc[i]; ucursor[base + i] = ex + loc[i]; }
        if (t == 255) ustart[2048] = E_;
        return;
    }
    int dir = blk >> 8;
    const float* wih = dir ? wihb : wihf;
    float bias = dir ? (bihb[t] + bhhb[t]) : (bihf[t] + bhhf[t]);
    int r0 = (blk & 255) * 32;

    float4 wv[16];
#pragma unroll
    for (int c = 0; c < 16; c++) wv[c] = ((const float4*)(wih + t * 64))[c];

#pragma unroll 2
    for (int ml = 0; ml < 32; ml++) {
        const float* xr = xg + (size_t)(r0 + ml) * 64;   // wave-uniform -> s_load
        float acc = bias;
#pragma unroll
        for (int c = 0; c < 16; c++) {
            float x0 = xr[4 * c], x1 = xr[4 * c + 1], x2 = xr[4 * c + 2], x3 = xr[4 * c + 3];
            acc += x0 * wv[c].x + x1 * wv[c].y + x2 * wv[c].z + x3 * wv[c].w;
        }
        pre[((size_t)dir * 8192 + r0 + ml) * 256 + t] = acc;   // gate-major, coalesced
    }
}

// ---------------- K_lstm: one WAVE per chain; W in VGPRs; readlane broadcast
// blocks 0..127: LSTM (64 threads); blocks 128..1151: counting-sort scatter.
__global__ __launch_bounds__(64, 1) void k_lstm(const float* __restrict__ pre,
                                                const float* __restrict__ whh_f,
                                                const float* __restrict__ whh_b,
                                                float* __restrict__ hgrp,
                                                const int* __restrict__ u,
                                                const int* __restrict__ v,
                                                int* __restrict__ ucursor,
                                                int2* __restrict__ eonv) {
    int blk = blockIdx.x;
    int t   = threadIdx.x;
    if (blk >= 128) {
        int n = (blk - 128) * 64 + t;
        int pos = atomicAdd(&ucursor[u[n]], 1);
        eonv[pos] = make_int2(n, v[n]);
        return;
    }
    int dir = blk >> 6;
    int b   = blk & 63;
    const float* whh = dir ? whh_b : whh_f;
    int e = t;                          // element this lane owns (0..63)

    // all 4 gate rows of W_hh for element e: 256 VGPRs
    float4 w0[16], w1[16], w2[16], w3[16];
#pragma unroll
    for (int c = 0; c < 16; c++) {
        w0[c] = ((const float4*)(whh + (size_t)(0 * 64 + e) * 64))[c];
        w1[c] = ((const float4*)(whh + (size_t)(1 * 64 + e) * 64))[c];
        w2[c] = ((const float4*)(whh + (size_t)(2 * 64 + e) * 64))[c];
        w3[c] = ((const float4*)(whh + (size_t)(3 * 64 + e) * 64))[c];
    }

    const float* prow = pre + ((size_t)dir * 8192 + (size_t)b * G_) * 256;
    float h = 0.f, cc = 0.f;
    int s0 = dir ? (G_ - 1) : 0;
    float p0 = prow[(size_t)s0 * 256 + e];
    float p1 = prow[(size_t)s0 * 256 + 64 + e];
    float p2 = prow[(size_t)s0 * 256 + 128 + e];
    float p3 = prow[(size_t)s0 * 256 + 192 + e];

    for (int k = 0; k < G_; k++) {
        int s = dir ? (G_ - 1 - k) : k;
        float a0 = p0, a1 = p1, a2 = p2, a3 = p3;
        if (k + 1 < G_) {
            int sn = dir ? (G_ - 2 - k) : (k + 1);
            const float* pr = prow + (size_t)sn * 256 + e;
            p0 = pr[0]; p1 = pr[64]; p2 = pr[128]; p3 = pr[192];
        }
        int hi = __float_as_int(h);
#pragma unroll
        for (int c = 0; c < 16; c++) {
            float f0 = __int_as_float(__builtin_amdgcn_readlane(hi, 4 * c + 0));
            float f1 = __int_as_float(__builtin_amdgcn_readlane(hi, 4 * c + 1));
            float f2 = __int_as_float(__builtin_amdgcn_readlane(hi, 4 * c + 2));
            float f3 = __int_as_float(__builtin_amdgcn_readlane(hi, 4 * c + 3));
            a0 += w0[c].x * f0 + w0[c].y * f1 + w0[c].z * f2 + w0[c].w * f3;
            a1 += w1[c].x * f0 + w1[c].y * f1 + w1[c].z * f2 + w1[c].w * f3;
            a2 += w2[c].x * f0 + w2[c].y * f1 + w2[c].z * f2 + w2[c].w * f3;
            a3 += w3[c].x * f0 + w3[c].y * f1 + w3[c].z * f2 + w3[c].w * f3;
        }
        // gate order: a0=i, a1=f, a2=g, a3=o
        float c2 = sigm(a1) * cc + sigm(a0) * tanh_fast(a2);
        float hh = sigm(a3) * tanh_fast(c2);
        cc = c2; h = hh;
        hgrp[((size_t)b * G_ + s) * 128 + dir * 64 + e] = hh;
    }
}

// ---------------- K3: hierarchical gather + K-sum ---------------------------
__global__ __launch_bounds__(128) void k_gather(const int* __restrict__ idx,
                                                const int* __restrict__ p2g,
                                                const float* __restrict__ hgrp,
                                                float* __restrict__ hnode) {
    int m = blockIdx.x;          // 0..2047
    int d = threadIdx.x;         // 0..127
    int b = m >> 5;
    float acc = 0.f;
#pragma unroll
    for (int k = 0; k < K_; k++) {
        int l = idx[m * K_ + k];
        int g = p2g[b * L_ + l];
        acc += hgrp[((size_t)b * G_ + g) * 128 + d];
    }
    hnode[(size_t)m * 128 + d] = acc;
}

// ---------------- K4a: edge-endpoint projections on distinct nodes ----------
__global__ __launch_bounds__(256) void k_proj(const float* __restrict__ hnode,
                                              const float* __restrict__ wsrc,
                                              const float* __restrict__ bsrc,
                                              const float* __restrict__ wdst,
                                              const float* __restrict__ bdst,
                                              float* __restrict__ Ps, float* __restrict__ Pd) {
    int m0 = blockIdx.x * 8;
    int t  = threadIdx.x;
    int ml = t >> 5, o = t & 31;
    // per-lane weight rows in registers (32 float4 each)
    float4 sw[32], dw[32];
#pragma unroll
    for (int c = 0; c < 32; c++) {
        sw[c] = ((const float4*)(wsrc + (size_t)o * 128))[c];
        dw[c] = ((const float4*)(wdst + (size_t)o * 128))[c];
    }
    const float* hr = hnode + (size_t)(m0 + ml) * 128;   // uniform per 32-lane group
    float accS = bsrc[o], accD = bdst[o];
#pragma unroll
    for (int c = 0; c < 32; c++) {
        float x0 = hr[4 * c], x1 = hr[4 * c + 1], x2 = hr[4 * c + 2], x3 = hr[4 * c + 3];
        accS += x0 * sw[c].x + x1 * sw[c].y + x2 * sw[c].z + x3 * sw[c].w;
        accD += x0 * dw[c].x + x1 * dw[c].y + x2 * dw[c].z + x3 * dw[c].w;
    }
    Ps[(size_t)(m0 + ml) * 32 + o] = accS;
    Pd[(size_t)(m0 + ml) * 32 + o] = accD;
}

// ---------------- K4b: count-weighted BatchNorm partial stats ---------------
__global__ __launch_bounds__(256) void k_bnstat(const float* __restrict__ Ps,
                                                 const float* __restrict__ Pd,
                                                 const int* __restrict__ cu,
                                                 const int* __restrict__ cv,
                                                 float* __restrict__ bn_raw) {
    int side = blockIdx.x & 1, sl = blockIdx.x >> 1;   // 32 slices of 64 m
    const float* P  = side ? Pd : Ps;
    const int*   cn = side ? cv : cu;
    int t = threadIdx.x;
    int mp = t >> 5, o = t & 31;
    float s1 = 0.f, s2 = 0.f;
#pragma unroll
    for (int i = 0; i < 8; i++) {
        int m = sl * 64 + i * 8 + mp;
        float c = (float)cn[m];
        float x = P[(size_t)m * 32 + o];
        s1 += c * x;
        s2 += c * x * x;
    }
    __shared__ float r1[256], r2[256];
    r1[t] = s1; r2[t] = s2;
    __syncthreads();
    for (int off = 128; off >= 32; off >>= 1) {
        if (t < off) { r1[t] += r1[t + off]; r2[t] += r2[t + off]; }
        __syncthreads();
    }
    if (t < 32) {
        atomicAdd(&bn_raw[side * 64 + t], r1[t]);
        atomicAdd(&bn_raw[side * 64 + 32 + t], r2[t]);
    }
}

// ---------------- K_prep: BN-normalize (inline finalize) + build waug -------
// waug layout: waug[i*COLS + j*256 + rh]
// i<32,j<32: ntl_w[rh,i,j]; i<32,j=32: ntl_v[rh,i]; i=32,j<32: ntl_v[rh,32+j]; i=32,j=32: ntl_b[rh]
__global__ __launch_bounds__(256) void k_prep(const float* __restrict__ Ps,
                                              const float* __restrict__ Pd,
                                              const float* __restrict__ bn_raw,
                                              const float* __restrict__ gs,
                                              const float* __restrict__ bes,
                                              const float* __restrict__ gd,
                                              const float* __restrict__ bed,
                                              const float* __restrict__ ntlw,
                                              const float* __restrict__ ntlv,
                                              const float* __restrict__ ntlb,
                                              float* __restrict__ hsaug,
                                              float* __restrict__ htaug,
                                              float* __restrict__ waug) {
    int blk = blockIdx.x;
    int t   = threadIdx.x;
    constexpr float invE = 1.f / (float)E_;
    if (blk < 576) {                     // 2048*2*36 / 256
        int gid = blk * 256 + t;
        int m = gid / (2 * STRD), s2 = gid % (2 * STRD);
        if (s2 < STRD) {
            int i = s2;
            float val = 0.f;
            if (i < 32) {
                float mu  = bn_raw[i] * invE;
                float isd = rsqrtf(bn_raw[32 + i] * invE - mu * mu + 1e-5f);
                val = gs[i] * (Ps[(size_t)m * 32 + i] - mu) * isd + bes[i];
            } else if (i == 32) val = 1.f;
            hsaug[(size_t)m * STRD + i] = val;
        } else {
            int j = s2 - STRD;
            float val = 0.f;
            if (j < 32) {
                float mu  = bn_raw[64 + j] * invE;
                float isd = rsqrtf(bn_raw[96 + j] * invE - mu * mu + 1e-5f);
                val = gd[j] * (Pd[(size_t)m * 32 + j] - mu) * isd + bed[j];
            } else if (j == 32) val = 1.f;
            htaug[(size_t)m * STRD + j] = val;
        }
        return;
    }
    int gid = (blk - 576) * 256 + t;      // JA*COLS = 1089*256
    int i   = gid / COLS;
    int rem = gid - i * COLS;
    int j   = rem >> 8;
    int rh  = rem & 255;
    float val;
    if (i < 32) val = (j < 32) ? ntlw[((size_t)rh * 32 + i) * 32 + j] : ntlv[rh * 64 + i];
    else        val = (j < 32) ? ntlv[rh * 64 + 32 + j] : ntlb[rh];
    waug[gid] = val;
}

// ---------------- K5b: A[m][j*256+rh] = sum_i hsaug[m,i]*waug[i][j*256+rh] --
__global__ __launch_bounds__(256) void k_agemm(const float* __restrict__ hsaug,
                                               const float* __restrict__ waug,
                                               __hip_bfloat16* __restrict__ A) {
    int mt = blockIdx.x;                   // 64 tiles of 32 m
    int j  = blockIdx.y;                   // 33
    int t  = threadIdx.x;                  // rh
    float w[JA];
#pragma unroll
    for (int i = 0; i < JA; i++) w[i] = waug[(size_t)i * COLS + j * 256 + t];

#pragma unroll 2
    for (int ml = 0; ml < 32; ml++) {
        const float* hr = hsaug + (size_t)(mt * 32 + ml) * STRD;   // uniform -> s_load
        float a0 = 0.f, a1 = 0.f;
#pragma unroll
        for (int i = 0; i < 32; i += 2) {
            a0 += hr[i] * w[i];
            a1 += hr[i + 1] * w[i + 1];
        }
        float acc = a0 + a1 + hr[32] * w[32];
        A[(size_t)(mt * 32 + ml) * COLS + j * 256 + t] = __float2bfloat16(acc);
    }
}

// ---------------- K6: z[n][rh] = A[u] . ht_aug[v]; LN partial stats ---------
DEV void load_ht(float* d, const float* __restrict__ htaug, int vv) {
    const float* hp = htaug + (size_t)vv * STRD;
#pragma unroll
    for (int j = 0; j < JA; j++) d[j] = hp[j];
}
DEV void edge_compute(const float* av, const float* ht, int n, int t,
                      __hip_bfloat16* __restrict__ z, float& s1, float& s2) {
    float a0 = 0.f, a1 = 0.f;
#pragma unroll
    for (int j = 0; j < 32; j += 2) {
        a0 += av[j] * ht[j];
        a1 += av[j + 1] * ht[j + 1];
    }
    float acc = a0 + a1 + av[32] * ht[32];
    z[(size_t)n * 256 + t] = __float2bfloat16(acc);
    s1 += acc; s2 += acc * acc;
}

__global__ __launch_bounds__(256) void k_z(const __hip_bfloat16* __restrict__ A,
                                           const float* __restrict__ htaug,
                                           const int* __restrict__ ustart,
                                           const int2* __restrict__ eonv,
                                           __hip_bfloat16* __restrict__ z,
                                           float* __restrict__ zsum,
                                           float* __restrict__ zsq) {
    int t = threadIdx.x;
    float s1 = 0.f, s2 = 0.f;
    for (int ui = 0; ui < 4; ui++) {
        int uu = blockIdx.x * 4 + ui;
        float av[JA];
#pragma unroll
        for (int j = 0; j < JA; j++)
            av[j] = __bfloat162float(A[(size_t)uu * COLS + j * 256 + t]);   // coalesced
        int e0 = ustart[uu], e1 = ustart[uu + 1];
        if (e0 >= e1) continue;
        int e = e0;
        int2 q0 = eonv[e];
        int n0 = rfl(q0.x), v0 = rfl(q0.y);
        float ht0[JA]; load_ht(ht0, htaug, v0);
        int n1 = 0, v1 = 0; float ht1[JA];
        while (true) {
            if (e + 1 < e1) {
                int2 q = eonv[e + 1];
                n1 = rfl(q.x); v1 = rfl(q.y);
                load_ht(ht1, htaug, v1);
            }
            edge_compute(av, ht0, n0, t, z, s1, s2);
            if (++e >= e1) break;
            if (e + 1 < e1) {
                int2 q = eonv[e + 1];
                n0 = rfl(q.x); v0 = rfl(q.y);
                load_ht(ht0, htaug, v0);
            }
            edge_compute(av, ht1, n1, t, z, s1, s2);
            if (++e >= e1) break;
        }
    }
    atomicAdd(&zsum[t], s1);
    atomicAdd(&zsq[t], s2);
}

// ---------------- K8: LN (stats inline) + tanh + contract to logits ---------
__global__ __launch_bounds__(256) void k_logit(const __hip_bfloat16* __restrict__ z,
                                               const float* __restrict__ zsum,
                                               const float* __restrict__ zsq,
                                               const float* __restrict__ ntlu,
                                               const float* __restrict__ ntlg,
                                               const float* __restrict__ ntlbe,
                                               float* __restrict__ out) {
    int t  = threadIdx.x;                 // rh = r*16+h
    int n0 = blockIdx.x * 16;
    float mu  = zsum[t] / (float)E_;
    float var = zsq[t] / (float)E_ - mu * mu;
    float isd = rsqrtf(var + 1e-5f);
    float g   = ntlg[t],  be  = ntlbe[t];
    float uw  = ntlu[t];                  // ntl_u[r,0,h] flat = rh
    float zv[16];
#pragma unroll
    for (int nl = 0; nl < 16; nl++)
        zv[nl] = __bfloat162float(z[(size_t)(n0 + nl) * 256 + t]);
#pragma unroll 1
    for (int nl = 0; nl < 16; nl++) {
        float zn  = g * (zv[nl] - mu) * isd + be;
        float val = uw * tanh_fast(zn);
        val += __shfl_xor(val, 1);
        val += __shfl_xor(val, 2);
        val += __shfl_xor(val, 4);
        val += __shfl_xor(val, 8);
        if ((t & 15) == 0) out[(size_t)(n0 + nl) * 16 + (t >> 4)] = val;
    }
}

// ============================ host side =====================================
extern "C" void kernel_launch(void* const* d_in, const int* in_sizes, int n_in,
                              void* d_out, int out_size, void* d_ws, size_t ws_size,
                              hipStream_t stream) {
    const int*   seq   = (const int*)d_in[0];
    const int*   p2g   = (const int*)d_in[1];
    const int*   idx   = (const int*)d_in[2];
    const int*   u     = (const int*)d_in[3];
    const int*   v     = (const int*)d_in[4];
    const float* emb   = (const float*)d_in[5];
    const float* wihf  = (const float*)d_in[6];
    const float* whhf  = (const float*)d_in[7];
    const float* bihf  = (const float*)d_in[8];
    const float* bhhf  = (const float*)d_in[9];
    const float* wihb  = (const float*)d_in[10];
    const float* whhb  = (const float*)d_in[11];
    const float* bihb  = (const float*)d_in[12];
    const float* bhhb  = (const float*)d_in[13];
    const float* wsrc  = (const float*)d_in[14];
    const float* bsrc  = (const float*)d_in[15];
    const float* wdst  = (const float*)d_in[16];
    const float* bdst  = (const float*)d_in[17];
    const float* gs    = (const float*)d_in[18];
    const float* bes   = (const float*)d_in[19];
    const float* gd    = (const float*)d_in[20];
    const float* bed   = (const float*)d_in[21];
    const float* ntlw  = (const float*)d_in[22];
    const float* ntlv  = (const float*)d_in[23];
    const float* ntlb  = (const float*)d_in[24];
    const float* ntlu  = (const float*)d_in[25];
    const float* ntlg  = (const float*)d_in[26];
    const float* ntlbe = (const float*)d_in[27];
    float* out = (float*)d_out;

    char* ws = (char*)d_ws;
    size_t off = 0;
    auto take = [&](size_t bytes) -> char* {
        char* p = ws + off;
        off = (off + bytes + 255) & ~(size_t)255;
        return p;
    };
    // zeroed region (contiguous, one memset)
    int*   cnt_u  = (int*)  take(2048 * 4);
    int*   cnt_v  = (int*)  take(2048 * 4);
    float* zsum   = (float*)take(256 * 4);
    float* zsq    = (float*)take(256 * 4);
    float* bn_raw = (float*)take(128 * 4);
    size_t zero_bytes = off;
    // rest
    float* x_grp   = (float*)take((size_t)B_ * G_ * 64 * 4);
    int*   ucursor = (int*)  take(2048 * 4);
    int*   ustart  = (int*)  take(2049 * 4);
    int2*  eonv    = (int2*) take((size_t)E_ * 8);
    float* pre     = (float*)take((size_t)2 * 8192 * 256 * 4);
    float* hgrp    = (float*)take((size_t)B_ * G_ * 128 * 4);
    float* hnode   = (float*)take((size_t)M_ * 128 * 4);
    float* Psrc    = (float*)take((size_t)M_ * 32 * 4);
    float* Pdst    = (float*)take((size_t)M_ * 32 * 4);
    float* hsaug   = (float*)take((size_t)M_ * STRD * 4);
    float* htaug   = (float*)take((size_t)M_ * STRD * 4);
    float* waug    = (float*)take((size_t)JA * COLS * 4);
    __hip_bfloat16* Abuf = (__hip_bfloat16*)take((size_t)M_ * COLS * 2);
    __hip_bfloat16* zbuf = (__hip_bfloat16*)take((size_t)E_ * 256 * 2);
    (void)ws_size; (void)in_sizes; (void)n_in; (void)out_size;

    hipMemsetAsync(d_ws, 0, zero_bytes, stream);

    k_eh<<<320, 256, 0, stream>>>(seq, p2g, emb, u, v, x_grp, cnt_u, cnt_v);
    k_pre<<<513, 256, 0, stream>>>(x_grp, wihf, bihf, bhhf, wihb, bihb, bhhb, pre,
                                   cnt_u, ustart, ucursor);
    k_lstm<<<128 + 1024, 64, 0, stream>>>(pre, whhf, whhb, hgrp, u, v, ucursor, eonv);
    k_gather<<<M_, 128, 0, stream>>>(idx, p2g, hgrp, hnode);
    k_proj<<<M_ / 8, 256, 0, stream>>>(hnode, wsrc, bsrc, wdst, bdst, Psrc, Pdst);
    k_bnstat<<<64, 256, 0, stream>>>(Psrc, Pdst, cnt_u, cnt_v, bn_raw);
    k_prep<<<576 + 1089, 256, 0, stream>>>(Psrc, Pdst, bn_raw, gs, bes, gd, bed,
                                           ntlw, ntlv, ntlb, hsaug, htaug, waug);
    k_agemm<<<dim3(64, JA), 256, 0, stream>>>(hsaug, waug, Abuf);
    k_z<<<M_ / 4, 256, 0, stream>>>(Abuf, htaug, ustart, eonv, zbuf, zsum, zsq);
    k_logit<<<E_ / 16, 256, 0, stream>>>(zbuf, zsum, zsq, ntlu, ntlg, ntlbe, out);
}

// Round 4
// 428.886 us; speedup vs baseline: 1.1605x; 1.1605x over previous
//
#include <hip/hip_runtime.h>
#include <hip/hip_bf16.h>
#include <cstdint>

// Problem constants
constexpr int B_   = 64;
constexpr int L_   = 512;
constexpr int G_   = 128;
constexpr int E_   = 65536;
constexpr int RH   = 256;    // NREL*NHID
constexpr int M_   = 2048;   // B*N distinct nodes
constexpr int JA   = 33;     // augmented j (32 + const-1 slot)
constexpr int COLS = RH * JA;   // 8448
constexpr int STRD = 36;        // padded row stride for hs/ht (float4-friendly)
constexpr int K_   = 8;

#define DEV static __device__ __forceinline__

DEV float sigm(float x) { return 1.f / (1.f + __expf(-x)); }
DEV float tanh_fast(float x) {
    x = fminf(15.f, fmaxf(-15.f, x));
    float e = __expf(2.f * x);
    return (e - 1.f) / (e + 1.f);
}
DEV int rfl(int x) { return __builtin_amdgcn_readfirstlane(x); }

// ---------------- K_eh: embed (LDS-atomic scatter) + edge histograms --------
__global__ __launch_bounds__(256) void k_eh(const int* __restrict__ seq,
                                            const int* __restrict__ p2g,
                                            const float* __restrict__ emb,
                                            const int* __restrict__ u,
                                            const int* __restrict__ v,
                                            float* __restrict__ xg,
                                            int* __restrict__ cu, int* __restrict__ cv) {
    int blk = blockIdx.x;
    int t   = threadIdx.x;
    if (blk >= 64) {
        int n = (blk - 64) * 256 + t;
        atomicAdd(&cu[u[n]], 1);
        atomicAdd(&cv[v[n]], 1);
        return;
    }
    __shared__ float xgl[G_ * 64];          // 32 KB
    for (int i = t; i < G_ * 64; i += 256) xgl[i] = 0.f;
    __syncthreads();
    int b = blk;
    int d = t & 63, part = t >> 6;
#pragma unroll 8
    for (int l = part; l < L_; l += 4) {     // l uniform per wave -> scalar loads
        int s = seq[b * L_ + l];
        int g = p2g[b * L_ + l];
        atomicAdd(&xgl[g * 64 + d], emb[s * 64 + d]);
    }
    __syncthreads();
    for (int i = t; i < G_ * 64; i += 256) xg[(size_t)b * G_ * 64 + i] = xgl[i];
}

// ---------------- K_pre: input-gate GEMM (scalar x broadcast) + scan --------
__global__ __launch_bounds__(256) void k_pre(const float* __restrict__ xg,
                                             const float* __restrict__ wihf,
                                             const float* __restrict__ bihf,
                                             const float* __restrict__ bhhf,
                                             const float* __restrict__ wihb,
                                             const float* __restrict__ bihb,
                                             const float* __restrict__ bhhb,
                                             float* __restrict__ pre,
                                             const int* __restrict__ cu,
                                             int* __restrict__ ustart,
                                             int* __restrict__ ucursor) {
    int blk = blockIdx.x;
    int t   = threadIdx.x;
    if (blk == 512) {
        __shared__ int ps[256];
        int base = t * 8, run = 0;
        int c[8], loc[8];
#pragma unroll
        for (int i = 0; i < 8; i++) c[i] = cu[base + i];
#pragma unroll
        for (int i = 0; i < 8; i++) { loc[i] = run; run += c[i]; }
        ps[t] = run;
        __syncthreads();
        for (int off = 1; off < 256; off <<= 1) {
            int a = (t >= off) ? ps[t - off] : 0;
            __syncthreads();
            ps[t] += a;
            __syncthreads();
        }
        int ex = ps[t] - run;
#pragma unroll
        for (int i = 0; i < 8; i++) { ustart[base + i] = ex + loc[i]; ucursor[base + i] = ex + loc[i]; }
        if (t == 255) ustart[2048] = E_;
        return;
    }
    int dir = blk >> 8;
    const float* wih = dir ? wihb : wihf;
    float bias = dir ? (bihb[t] + bhhb[t]) : (bihf[t] + bhhf[t]);
    int r0 = (blk & 255) * 32;

    float4 wv[16];
#pragma unroll
    for (int c = 0; c < 16; c++) wv[c] = ((const float4*)(wih + t * 64))[c];

#pragma unroll 2
    for (int ml = 0; ml < 32; ml++) {
        const float* xr = xg + (size_t)(r0 + ml) * 64;   // wave-uniform -> s_load
        float acc = bias;
#pragma unroll
        for (int c = 0; c < 16; c++) {
            float x0 = xr[4 * c], x1 = xr[4 * c + 1], x2 = xr[4 * c + 2], x3 = xr[4 * c + 3];
            acc += x0 * wv[c].x + x1 * wv[c].y + x2 * wv[c].z + x3 * wv[c].w;
        }
        pre[((size_t)dir * 8192 + r0 + ml) * 256 + t] = acc;   // gate-major, coalesced
    }
}

// ---------------- K_lstm: 256 thr/chain, pre staged in LDS (2x64-step chunks),
// gates pre-activated in parallel before exchange. blocks 128..383: edge sort.
__global__ __launch_bounds__(256, 1) void k_lstm(const float* __restrict__ pre,
                                                 const float* __restrict__ whh_f,
                                                 const float* __restrict__ whh_b,
                                                 float* __restrict__ hgrp,
                                                 const int* __restrict__ u,
                                                 const int* __restrict__ v,
                                                 int* __restrict__ ucursor,
                                                 int2* __restrict__ eonv) {
    int blk = blockIdx.x;
    int t   = threadIdx.x;
    if (blk >= 128) {
        int n = (blk - 128) * 256 + t;
        int pos = atomicAdd(&ucursor[u[n]], 1);
        eonv[pos] = make_int2(n, v[n]);
        return;
    }
    __shared__ __align__(16) float plds[64][256];   // 64 KB: one 64-step chunk
    __shared__ __align__(16) float hl[2][64];
    __shared__ float gl[256];
    int dir = blk >> 6;
    int b   = blk & 63;
    const float* whh = dir ? whh_b : whh_f;
    const float* src = pre + ((size_t)dir * 8192 + (size_t)b * G_) * 256;

    float4 wv[16];                       // W_hh row t (gate q=t>>6, elem e=t&63)
#pragma unroll
    for (int c = 0; c < 16; c++) wv[c] = ((const float4*)(whh + t * 64))[c];

    {   // stage chunk 0 (steps k=0..63)
        int base = dir ? 64 : 0;
        const float4* s4 = (const float4*)(src + (size_t)base * 256);
        float4* d4 = (float4*)&plds[0][0];
#pragma unroll
        for (int i = 0; i < 16; i++) d4[i * 256 + t] = s4[i * 256 + t];
    }
    if (t < 64) hl[0][t] = 0.f;
    float creg = 0.f;
    __syncthreads();
    int q = t >> 6;

    for (int half = 0; half < 2; half++) {
        if (half == 1) {                 // reload chunk 1 (steps k=64..127)
            int base = dir ? 0 : 64;
            const float4* s4 = (const float4*)(src + (size_t)base * 256);
            float4* d4 = (float4*)&plds[0][0];
#pragma unroll
            for (int i = 0; i < 16; i++) d4[i * 256 + t] = s4[i * 256 + t];
            __syncthreads();
        }
        for (int kk = 0; kk < 64; kk++) {
            int k = half * 64 + kk;
            int s = dir ? (G_ - 1 - k) : k;
            float p = plds[s & 63][t];
            const float4* hp = (const float4*)hl[k & 1];
            float a0 = p, a1 = 0.f, a2 = 0.f, a3 = 0.f;
#pragma unroll
            for (int c = 0; c < 16; c += 4) {
                float4 h0 = hp[c], h1 = hp[c + 1], h2 = hp[c + 2], h3 = hp[c + 3];
                a0 += h0.x * wv[c].x     + h0.y * wv[c].y     + h0.z * wv[c].z     + h0.w * wv[c].w;
                a1 += h1.x * wv[c + 1].x + h1.y * wv[c + 1].y + h1.z * wv[c + 1].z + h1.w * wv[c + 1].w;
                a2 += h2.x * wv[c + 2].x + h2.y * wv[c + 2].y + h2.z * wv[c + 2].z + h2.w * wv[c + 2].w;
                a3 += h3.x * wv[c + 3].x + h3.y * wv[c + 3].y + h3.z * wv[c + 3].z + h3.w * wv[c + 3].w;
            }
            float g = (a0 + a1) + (a2 + a3);
            // pre-activate own gate IN PARALLEL (q: 0=i,1=f,2=g,3=o)
            gl[t] = (q == 2) ? tanh_fast(g) : sigm(g);
            __syncthreads();
            if (t < 64) {
                float ai = gl[t], af = gl[64 + t], ag = gl[128 + t], ao = gl[192 + t];
                float c2 = af * creg + ai * ag;
                float hh = ao * tanh_fast(c2);
                creg = c2;
                hl[(k + 1) & 1][t] = hh;
                hgrp[((size_t)(b * G_ + s)) * 128 + dir * 64 + t] = hh;
            }
            __syncthreads();
        }
    }
}

// ---------------- K3: hierarchical gather + K-sum ---------------------------
__global__ __launch_bounds__(128) void k_gather(const int* __restrict__ idx,
                                                const int* __restrict__ p2g,
                                                const float* __restrict__ hgrp,
                                                float* __restrict__ hnode) {
    int m = blockIdx.x;          // 0..2047
    int d = threadIdx.x;         // 0..127
    int b = m >> 5;
    float acc = 0.f;
#pragma unroll
    for (int k = 0; k < K_; k++) {
        int l = idx[m * K_ + k];
        int g = p2g[b * L_ + l];
        acc += hgrp[((size_t)b * G_ + g) * 128 + d];
    }
    hnode[(size_t)m * 128 + d] = acc;
}

// ---------------- K4a: edge-endpoint projections on distinct nodes ----------
__global__ __launch_bounds__(256) void k_proj(const float* __restrict__ hnode,
                                              const float* __restrict__ wsrc,
                                              const float* __restrict__ bsrc,
                                              const float* __restrict__ wdst,
                                              const float* __restrict__ bdst,
                                              float* __restrict__ Ps, float* __restrict__ Pd) {
    int m0 = blockIdx.x * 8;
    int t  = threadIdx.x;
    int ml = t >> 5, o = t & 31;
    float4 sw[32], dw[32];
#pragma unroll
    for (int c = 0; c < 32; c++) {
        sw[c] = ((const float4*)(wsrc + (size_t)o * 128))[c];
        dw[c] = ((const float4*)(wdst + (size_t)o * 128))[c];
    }
    const float* hr = hnode + (size_t)(m0 + ml) * 128;
    float accS = bsrc[o], accD = bdst[o];
#pragma unroll
    for (int c = 0; c < 32; c++) {
        float x0 = hr[4 * c], x1 = hr[4 * c + 1], x2 = hr[4 * c + 2], x3 = hr[4 * c + 3];
        accS += x0 * sw[c].x + x1 * sw[c].y + x2 * sw[c].z + x3 * sw[c].w;
        accD += x0 * dw[c].x + x1 * dw[c].y + x2 * dw[c].z + x3 * dw[c].w;
    }
    Ps[(size_t)(m0 + ml) * 32 + o] = accS;
    Pd[(size_t)(m0 + ml) * 32 + o] = accD;
}

// ---------------- K4b: count-weighted BatchNorm partial stats ---------------
__global__ __launch_bounds__(256) void k_bnstat(const float* __restrict__ Ps,
                                                 const float* __restrict__ Pd,
                                                 const int* __restrict__ cu,
                                                 const int* __restrict__ cv,
                                                 float* __restrict__ bn_raw) {
    int side = blockIdx.x & 1, sl = blockIdx.x >> 1;   // 32 slices of 64 m
    const float* P  = side ? Pd : Ps;
    const int*   cn = side ? cv : cu;
    int t = threadIdx.x;
    int mp = t >> 5, o = t & 31;
    float s1 = 0.f, s2 = 0.f;
#pragma unroll
    for (int i = 0; i < 8; i++) {
        int m = sl * 64 + i * 8 + mp;
        float c = (float)cn[m];
        float x = P[(size_t)m * 32 + o];
        s1 += c * x;
        s2 += c * x * x;
    }
    __shared__ float r1[256], r2[256];
    r1[t] = s1; r2[t] = s2;
    __syncthreads();
    for (int off = 128; off >= 32; off >>= 1) {
        if (t < off) { r1[t] += r1[t + off]; r2[t] += r2[t + off]; }
        __syncthreads();
    }
    if (t < 32) {
        atomicAdd(&bn_raw[side * 64 + t], r1[t]);
        atomicAdd(&bn_raw[side * 64 + 32 + t], r2[t]);
    }
}

// ---------------- K_prep: BN-normalize (inline finalize) + build waug -------
// waug layout: waug[i*COLS + j*256 + rh]
__global__ __launch_bounds__(256) void k_prep(const float* __restrict__ Ps,
                                              const float* __restrict__ Pd,
                                              const float* __restrict__ bn_raw,
                                              const float* __restrict__ gs,
                                              const float* __restrict__ bes,
                                              const float* __restrict__ gd,
                                              const float* __restrict__ bed,
                                              const float* __restrict__ ntlw,
                                              const float* __restrict__ ntlv,
                                              const float* __restrict__ ntlb,
                                              float* __restrict__ hsaug,
                                              float* __restrict__ htaug,
                                              float* __restrict__ waug) {
    int blk = blockIdx.x;
    int t   = threadIdx.x;
    constexpr float invE = 1.f / (float)E_;
    if (blk < 576) {                     // 2048*2*36 / 256
        int gid = blk * 256 + t;
        int m = gid / (2 * STRD), s2 = gid % (2 * STRD);
        if (s2 < STRD) {
            int i = s2;
            float val = 0.f;
            if (i < 32) {
                float mu  = bn_raw[i] * invE;
                float isd = rsqrtf(bn_raw[32 + i] * invE - mu * mu + 1e-5f);
                val = gs[i] * (Ps[(size_t)m * 32 + i] - mu) * isd + bes[i];
            } else if (i == 32) val = 1.f;
            hsaug[(size_t)m * STRD + i] = val;
        } else {
            int j = s2 - STRD;
            float val = 0.f;
            if (j < 32) {
                float mu  = bn_raw[64 + j] * invE;
                float isd = rsqrtf(bn_raw[96 + j] * invE - mu * mu + 1e-5f);
                val = gd[j] * (Pd[(size_t)m * 32 + j] - mu) * isd + bed[j];
            } else if (j == 32) val = 1.f;
            htaug[(size_t)m * STRD + j] = val;
        }
        return;
    }
    // j-fastest order: coalesced ntlw reads; scattered (fire-and-forget) writes
    int gid = (blk - 576) * 256 + t;      // over JA*COLS
    int i   = gid / COLS;
    int rem = gid - i * COLS;
    int rh  = rem / JA;
    int j   = rem - rh * JA;
    float val;
    if (i < 32) val = (j < 32) ? ntlw[((size_t)rh * 32 + i) * 32 + j] : ntlv[rh * 64 + i];
    else        val = (j < 32) ? ntlv[rh * 64 + 32 + j] : ntlb[rh];
    waug[(size_t)i * COLS + j * 256 + rh] = val;
}

// ---------------- K5b: A[m][j*256+rh] = sum_i hsaug[m,i]*waug[i][j*256+rh] --
__global__ __launch_bounds__(256) void k_agemm(const float* __restrict__ hsaug,
                                               const float* __restrict__ waug,
                                               __hip_bfloat16* __restrict__ A) {
    int mt = blockIdx.x;                   // 64 tiles of 32 m
    int j  = blockIdx.y;                   // 33
    int t  = threadIdx.x;                  // rh
    float w[JA];
#pragma unroll
    for (int i = 0; i < JA; i++) w[i] = waug[(size_t)i * COLS + j * 256 + t];

#pragma unroll 2
    for (int ml = 0; ml < 32; ml++) {
        const float* hr = hsaug + (size_t)(mt * 32 + ml) * STRD;   // uniform -> s_load
        float a0 = 0.f, a1 = 0.f;
#pragma unroll
        for (int i = 0; i < 32; i += 2) {
            a0 += hr[i] * w[i];
            a1 += hr[i + 1] * w[i + 1];
        }
        float acc = a0 + a1 + hr[32] * w[32];
        A[(size_t)(mt * 32 + ml) * COLS + j * 256 + t] = __float2bfloat16(acc);
    }
}

// ---------------- K6: z[n][rh] = A[u] . ht_aug[v]; LN partial stats ---------
DEV void load_ht(float* d, const float* __restrict__ htaug, int vv) {
    const float* hp = htaug + (size_t)vv * STRD;
#pragma unroll
    for (int j = 0; j < JA; j++) d[j] = hp[j];
}
DEV void edge_compute(const float* av, const float* ht, int n, int t,
                      __hip_bfloat16* __restrict__ z, float& s1, float& s2) {
    float a0 = 0.f, a1 = 0.f;
#pragma unroll
    for (int j = 0; j < 32; j += 2) {
        a0 += av[j] * ht[j];
        a1 += av[j + 1] * ht[j + 1];
    }
    float acc = a0 + a1 + av[32] * ht[32];
    z[(size_t)n * 256 + t] = __float2bfloat16(acc);
    s1 += acc; s2 += acc * acc;
}

__global__ __launch_bounds__(256) void k_z(const __hip_bfloat16* __restrict__ A,
                                           const float* __restrict__ htaug,
                                           const int* __restrict__ ustart,
                                           const int2* __restrict__ eonv,
                                           __hip_bfloat16* __restrict__ z,
                                           float* __restrict__ zsum,
                                           float* __restrict__ zsq) {
    int t = threadIdx.x;
    float s1 = 0.f, s2 = 0.f;
    for (int ui = 0; ui < 4; ui++) {
        int uu = blockIdx.x * 4 + ui;
        float av[JA];
#pragma unroll
        for (int j = 0; j < JA; j++)
            av[j] = __bfloat162float(A[(size_t)uu * COLS + j * 256 + t]);   // coalesced
        int e0 = ustart[uu], e1 = ustart[uu + 1];
        if (e0 >= e1) continue;
        int e = e0;
        int2 q0 = eonv[e];
        int n0 = rfl(q0.x), v0 = rfl(q0.y);
        float ht0[JA]; load_ht(ht0, htaug, v0);
        int n1 = 0, v1 = 0; float ht1[JA];
        while (true) {
            if (e + 1 < e1) {
                int2 q = eonv[e + 1];
                n1 = rfl(q.x); v1 = rfl(q.y);
                load_ht(ht1, htaug, v1);
            }
            edge_compute(av, ht0, n0, t, z, s1, s2);
            if (++e >= e1) break;
            if (e + 1 < e1) {
                int2 q = eonv[e + 1];
                n0 = rfl(q.x); v0 = rfl(q.y);
                load_ht(ht0, htaug, v0);
            }
            edge_compute(av, ht1, n1, t, z, s1, s2);
            if (++e >= e1) break;
        }
    }
    atomicAdd(&zsum[t], s1);
    atomicAdd(&zsq[t], s2);
}

// ---------------- K8: LN (stats inline) + tanh + contract to logits ---------
__global__ __launch_bounds__(256) void k_logit(const __hip_bfloat16* __restrict__ z,
                                               const float* __restrict__ zsum,
                                               const float* __restrict__ zsq,
                                               const float* __restrict__ ntlu,
                                               const float* __restrict__ ntlg,
                                               const float* __restrict__ ntlbe,
                                               float* __restrict__ out) {
    int t  = threadIdx.x;                 // rh = r*16+h
    int n0 = blockIdx.x * 16;
    float mu  = zsum[t] / (float)E_;
    float var = zsq[t] / (float)E_ - mu * mu;
    float isd = rsqrtf(var + 1e-5f);
    float g   = ntlg[t],  be  = ntlbe[t];
    float uw  = ntlu[t];
    float zv[16];
#pragma unroll
    for (int nl = 0; nl < 16; nl++)
        zv[nl] = __bfloat162float(z[(size_t)(n0 + nl) * 256 + t]);
#pragma unroll 1
    for (int nl = 0; nl < 16; nl++) {
        float zn  = g * (zv[nl] - mu) * isd + be;
        float val = uw * tanh_fast(zn);
        val += __shfl_xor(val, 1);
        val += __shfl_xor(val, 2);
        val += __shfl_xor(val, 4);
        val += __shfl_xor(val, 8);
        if ((t & 15) == 0) out[(size_t)(n0 + nl) * 16 + (t >> 4)] = val;
    }
}

// ============================ host side =====================================
extern "C" void kernel_launch(void* const* d_in, const int* in_sizes, int n_in,
                              void* d_out, int out_size, void* d_ws, size_t ws_size,
                              hipStream_t stream) {
    const int*   seq   = (const int*)d_in[0];
    const int*   p2g   = (const int*)d_in[1];
    const int*   idx   = (const int*)d_in[2];
    const int*   u     = (const int*)d_in[3];
    const int*   v     = (const int*)d_in[4];
    const float* emb   = (const float*)d_in[5];
    const float* wihf  = (const float*)d_in[6];
    const float* whhf  = (const float*)d_in[7];
    const float* bihf  = (const float*)d_in[8];
    const float* bhhf  = (const float*)d_in[9];
    const float* wihb  = (const float*)d_in[10];
    const float* whhb  = (const float*)d_in[11];
    const float* bihb  = (const float*)d_in[12];
    const float* bhhb  = (const float*)d_in[13];
    const float* wsrc  = (const float*)d_in[14];
    const float* bsrc  = (const float*)d_in[15];
    const float* wdst  = (const float*)d_in[16];
    const float* bdst  = (const float*)d_in[17];
    const float* gs    = (const float*)d_in[18];
    const float* bes   = (const float*)d_in[19];
    const float* gd    = (const float*)d_in[20];
    const float* bed   = (const float*)d_in[21];
    const float* ntlw  = (const float*)d_in[22];
    const float* ntlv  = (const float*)d_in[23];
    const float* ntlb  = (const float*)d_in[24];
    const float* ntlu  = (const float*)d_in[25];
    const float* ntlg  = (const float*)d_in[26];
    const float* ntlbe = (const float*)d_in[27];
    float* out = (float*)d_out;

    char* ws = (char*)d_ws;
    size_t off = 0;
    auto take = [&](size_t bytes) -> char* {
        char* p = ws + off;
        off = (off + bytes + 255) & ~(size_t)255;
        return p;
    };
    // zeroed region (contiguous, one memset)
    int*   cnt_u  = (int*)  take(2048 * 4);
    int*   cnt_v  = (int*)  take(2048 * 4);
    float* zsum   = (float*)take(256 * 4);
    float* zsq    = (float*)take(256 * 4);
    float* bn_raw = (float*)take(128 * 4);
    size_t zero_bytes = off;
    // rest
    float* x_grp   = (float*)take((size_t)B_ * G_ * 64 * 4);
    int*   ucursor = (int*)  take(2048 * 4);
    int*   ustart  = (int*)  take(2049 * 4);
    int2*  eonv    = (int2*) take((size_t)E_ * 8);
    float* pre     = (float*)take((size_t)2 * 8192 * 256 * 4);
    float* hgrp    = (float*)take((size_t)B_ * G_ * 128 * 4);
    float* hnode   = (float*)take((size_t)M_ * 128 * 4);
    float* Psrc    = (float*)take((size_t)M_ * 32 * 4);
    float* Pdst    = (float*)take((size_t)M_ * 32 * 4);
    float* hsaug   = (float*)take((size_t)M_ * STRD * 4);
    float* htaug   = (float*)take((size_t)M_ * STRD * 4);
    float* waug    = (float*)take((size_t)JA * COLS * 4);
    __hip_bfloat16* Abuf = (__hip_bfloat16*)take((size_t)M_ * COLS * 2);
    __hip_bfloat16* zbuf = (__hip_bfloat16*)take((size_t)E_ * 256 * 2);
    (void)ws_size; (void)in_sizes; (void)n_in; (void)out_size;

    hipMemsetAsync(d_ws, 0, zero_bytes, stream);

    k_eh<<<320, 256, 0, stream>>>(seq, p2g, emb, u, v, x_grp, cnt_u, cnt_v);
    k_pre<<<513, 256, 0, stream>>>(x_grp, wihf, bihf, bhhf, wihb, bihb, bhhb, pre,
                                   cnt_u, ustart, ucursor);
    k_lstm<<<384, 256, 0, stream>>>(pre, whhf, whhb, hgrp, u, v, ucursor, eonv);
    k_gather<<<M_, 128, 0, stream>>>(idx, p2g, hgrp, hnode);
    k_proj<<<M_ / 8, 256, 0, stream>>>(hnode, wsrc, bsrc, wdst, bdst, Psrc, Pdst);
    k_bnstat<<<64, 256, 0, stream>>>(Psrc, Pdst, cnt_u, cnt_v, bn_raw);
    k_prep<<<576 + 1089, 256, 0, stream>>>(Psrc, Pdst, bn_raw, gs, bes, gd, bed,
                                           ntlw, ntlv, ntlb, hsaug, htaug, waug);
    k_agemm<<<dim3(64, JA), 256, 0, stream>>>(hsaug, waug, Abuf);
    k_z<<<M_ / 4, 256, 0, stream>>>(Abuf, htaug, ustart, eonv, zbuf, zsum, zsq);
    k_logit<<<E_ / 16, 256, 0, stream>>>(zbuf, zsum, zsq, ntlu, ntlg, ntlbe, out);
}

// Round 5
// 417.519 us; speedup vs baseline: 1.1921x; 1.0272x over previous
//
#include <hip/hip_runtime.h>
#include <hip/hip_bf16.h>
#include <cstdint>

// Problem constants
constexpr int B_   = 64;
constexpr int L_   = 512;
constexpr int G_   = 128;
constexpr int E_   = 65536;
constexpr int RH   = 256;    // NREL*NHID
constexpr int M_   = 2048;   // B*N distinct nodes
constexpr int JA   = 33;     // augmented j (32 + const-1 slot)
constexpr int COLS = RH * JA;   // 8448
constexpr int STRD = 36;        // padded row stride for hs/ht (float4-friendly)

#define DEV static __device__ __forceinline__

DEV float sigm(float x) { return 1.f / (1.f + __expf(-x)); }
DEV float tanh_fast(float x) {
    x = fminf(15.f, fmaxf(-15.f, x));
    float e = __expf(2.f * x);
    return (e - 1.f) / (e + 1.f);
}
DEV int rfl(int x) { return __builtin_amdgcn_readfirstlane(x); }
DEV float rdlane(float x, int lane) {
    return __int_as_float(__builtin_amdgcn_readlane(__float_as_int(x), lane));
}

// ---------------- K_eh: embed (LDS-atomic scatter) + edge histograms --------
__global__ __launch_bounds__(256) void k_eh(const int* __restrict__ seq,
                                            const int* __restrict__ p2g,
                                            const float* __restrict__ emb,
                                            const int* __restrict__ u,
                                            const int* __restrict__ v,
                                            float* __restrict__ xg,
                                            int* __restrict__ cu, int* __restrict__ cv) {
    int blk = blockIdx.x;
    int t   = threadIdx.x;
    if (blk >= 64) {
        int n = (blk - 64) * 256 + t;
        atomicAdd(&cu[u[n]], 1);
        atomicAdd(&cv[v[n]], 1);
        return;
    }
    __shared__ float xgl[G_ * 64];          // 32 KB
    for (int i = t; i < G_ * 64; i += 256) xgl[i] = 0.f;
    __syncthreads();
    int b = blk;
    int d = t & 63, part = t >> 6;
#pragma unroll 8
    for (int l = part; l < L_; l += 4) {
        int s = seq[b * L_ + l];
        int g = p2g[b * L_ + l];
        atomicAdd(&xgl[g * 64 + d], emb[s * 64 + d]);
    }
    __syncthreads();
    for (int i = t; i < G_ * 64; i += 256) xg[(size_t)b * G_ * 64 + i] = xgl[i];
}

// ---------------- K_pre: input-gate GEMM (scalar x broadcast) + scan --------
__global__ __launch_bounds__(256) void k_pre(const float* __restrict__ xg,
                                             const float* __restrict__ wihf,
                                             const float* __restrict__ bihf,
                                             const float* __restrict__ bhhf,
                                             const float* __restrict__ wihb,
                                             const float* __restrict__ bihb,
                                             const float* __restrict__ bhhb,
                                             float* __restrict__ pre,
                                             const int* __restrict__ cu,
                                             int* __restrict__ ustart,
                                             int* __restrict__ ucursor) {
    int blk = blockIdx.x;
    int t   = threadIdx.x;
    if (blk == 512) {
        __shared__ int ps[256];
        int base = t * 8, run = 0;
        int c[8], loc[8];
#pragma unroll
        for (int i = 0; i < 8; i++) c[i] = cu[base + i];
#pragma unroll
        for (int i = 0; i < 8; i++) { loc[i] = run; run += c[i]; }
        ps[t] = run;
        __syncthreads();
        for (int off = 1; off < 256; off <<= 1) {
            int a = (t >= off) ? ps[t - off] : 0;
            __syncthreads();
            ps[t] += a;
            __syncthreads();
        }
        int ex = ps[t] - run;
#pragma unroll
        for (int i = 0; i < 8; i++) { ustart[base + i] = ex + loc[i]; ucursor[base + i] = ex + loc[i]; }
        if (t == 255) ustart[2048] = E_;
        return;
    }
    int dir = blk >> 8;
    const float* wih = dir ? wihb : wihf;
    float bias = dir ? (bihb[t] + bhhb[t]) : (bihf[t] + bhhf[t]);
    int r0 = (blk & 255) * 32;

    float4 wv[16];
#pragma unroll
    for (int c = 0; c < 16; c++) wv[c] = ((const float4*)(wih + t * 64))[c];

#pragma unroll 2
    for (int ml = 0; ml < 32; ml++) {
        const float* xr = xg + (size_t)(r0 + ml) * 64;   // wave-uniform -> s_load
        float acc = bias;
#pragma unroll
        for (int c = 0; c < 16; c++) {
            float x0 = xr[4 * c], x1 = xr[4 * c + 1], x2 = xr[4 * c + 2], x3 = xr[4 * c + 3];
            acc += x0 * wv[c].x + x1 * wv[c].y + x2 * wv[c].z + x3 * wv[c].w;
        }
        pre[((size_t)dir * 8192 + r0 + ml) * 256 + t] = acc;   // gate-major, coalesced
    }
}

// ---------------- K_lstm: readlane-broadcast dot, 1 barrier/step, NO global
// store inside the barrier loop (h history flushed per 64-step half).
// blocks 128..383: edge counting-sort scatter.
__global__ __launch_bounds__(256, 1) void k_lstm(const float* __restrict__ pre,
                                                 const float* __restrict__ whh_f,
                                                 const float* __restrict__ whh_b,
                                                 float* __restrict__ hgrp,
                                                 const int* __restrict__ u,
                                                 const int* __restrict__ v,
                                                 int* __restrict__ ucursor,
                                                 int2* __restrict__ eonv) {
    int blk = blockIdx.x;
    int t   = threadIdx.x;
    if (blk >= 128) {
        int n = (blk - 128) * 256 + t;
        int pos = atomicAdd(&ucursor[u[n]], 1);
        eonv[pos] = make_int2(n, v[n]);
        return;
    }
    __shared__ __align__(16) float plds[64][256];   // 64 KB: one 64-step pre chunk
    __shared__ __align__(16) float hist[64][64];    // 16 KB: h history of the chunk
    __shared__ float gl[2][256];                    // activated-gate exchange
    int dir = blk >> 6;
    int b   = blk & 63;
    const float* whh = dir ? whh_b : whh_f;
    const float* src = pre + ((size_t)dir * 8192 + (size_t)b * G_) * 256;
    int e = t & 63;
    int q = t >> 6;                    // wave = gate (0=i,1=f,2=g,3=o)

    float4 wv[16];                     // W_hh row t
#pragma unroll
    for (int c = 0; c < 16; c++) wv[c] = ((const float4*)(whh + (size_t)t * 64))[c];

    float h = 0.f, creg = 0.f;         // lane e's h[e], c[e] (replicated per wave)

    for (int half = 0; half < 2; half++) {
        {   // stage 64-step pre chunk into LDS
            int base = (dir ^ half) ? 64 : 0;
            const float4* s4 = (const float4*)(src + (size_t)base * 256);
            float4* d4 = (float4*)&plds[0][0];
#pragma unroll
            for (int i = 0; i < 16; i++) d4[i * 256 + t] = s4[i * 256 + t];
        }
        __syncthreads();
        for (int kk = 0; kk < 64; kk++) {
            int k = half * 64 + kk;
            int srow = dir ? (63 - kk) : kk;
            float p = plds[srow][t];
            float a0 = p, a1 = 0.f, a2 = 0.f, a3 = 0.f;
#pragma unroll
            for (int c = 0; c < 16; c++) {
                float f0 = rdlane(h, 4 * c + 0);
                float f1 = rdlane(h, 4 * c + 1);
                float f2 = rdlane(h, 4 * c + 2);
                float f3 = rdlane(h, 4 * c + 3);
                a0 += wv[c].x * f0;
                a1 += wv[c].y * f1;
                a2 += wv[c].z * f2;
                a3 += wv[c].w * f3;
            }
            float g = (a0 + a1) + (a2 + a3);
            gl[k & 1][t] = (q == 2) ? tanh_fast(g) : sigm(g);   // pre-activate own gate
            __syncthreads();                                     // ONE barrier per step
            float ai = gl[k & 1][e];
            float af = gl[k & 1][64 + e];
            float ag = gl[k & 1][128 + e];
            float ao = gl[k & 1][192 + e];
            creg = af * creg + ai * ag;
            h = ao * tanh_fast(creg);          // every wave updates redundantly
            if (q == 0) hist[srow][e] = h;
        }
        __syncthreads();                        // hist complete, plds reads done
        // flush hist -> hgrp: s = (dir ? (1-half) : half)*64 + row
        int sbase = (dir ? (1 - half) : half) * 64;
#pragma unroll
        for (int i = 0; i < 16; i++) {
            int row = q * 16 + i;
            int s = sbase + row;
            hgrp[((size_t)(b * G_ + s)) * 128 + dir * 64 + e] = hist[row][e];
        }
        // next half's staging barrier (or kernel end) drains these stores
    }
}

// ---------------- K_gp: gather + projections + BN partial stats (fused) -----
__global__ __launch_bounds__(256) void k_gp(const int* __restrict__ idx,
                                            const int* __restrict__ p2g,
                                            const float* __restrict__ hgrp,
                                            const int* __restrict__ cu,
                                            const int* __restrict__ cv,
                                            const float* __restrict__ wsrc,
                                            const float* __restrict__ bsrc,
                                            const float* __restrict__ wdst,
                                            const float* __restrict__ bdst,
                                            float* __restrict__ Ps, float* __restrict__ Pd,
                                            float* __restrict__ bn_raw) {
    __shared__ __align__(16) float hsl[8][128];
    __shared__ float red[256];
    int m0 = blockIdx.x * 8;
    int t  = threadIdx.x;
    // phase 1: gather 8 node rows into LDS
    int d = t & 127, mh = t >> 7;
#pragma unroll
    for (int rep = 0; rep < 4; rep++) {
        int ml = rep * 2 + mh;
        int m  = m0 + ml;
        int b  = m >> 5;
        float acc = 0.f;
#pragma unroll
        for (int k = 0; k < 8; k++) {
            int l = idx[m * 8 + k];
            int g = p2g[b * L_ + l];
            acc += hgrp[((size_t)b * G_ + g) * 128 + d];
        }
        hsl[ml][d] = acc;
    }
    __syncthreads();
    // phase 2: proj (src then dst, weight regs reused) + count-weighted stats
    int ml = t >> 5, o = t & 31;
    int m  = m0 + ml;
    const float4* hp = (const float4*)&hsl[ml][0];
    float cw_u = (float)cu[m], cw_v = (float)cv[m];
#pragma unroll 1
    for (int side = 0; side < 2; side++) {
        const float* W = side ? wdst : wsrc;
        float4 wr[32];
#pragma unroll
        for (int c = 0; c < 32; c++) wr[c] = ((const float4*)(W + (size_t)o * 128))[c];
        float acc = side ? bdst[o] : bsrc[o];
#pragma unroll
        for (int c = 0; c < 32; c++) {
            float4 h4 = hp[c];
            acc += h4.x * wr[c].x + h4.y * wr[c].y + h4.z * wr[c].z + h4.w * wr[c].w;
        }
        (side ? Pd : Ps)[(size_t)m * 32 + o] = acc;
        float cw = side ? cw_v : cw_u;
        red[t] = cw * acc;
        __syncthreads();
        if (t < 32) {
            float s = 0.f;
#pragma unroll
            for (int i = 0; i < 8; i++) s += red[i * 32 + t];
            atomicAdd(&bn_raw[side * 64 + t], s);
        }
        __syncthreads();
        red[t] = cw * acc * acc;
        __syncthreads();
        if (t < 32) {
            float s = 0.f;
#pragma unroll
            for (int i = 0; i < 8; i++) s += red[i * 32 + t];
            atomicAdd(&bn_raw[side * 64 + 32 + t], s);
        }
        __syncthreads();
    }
}

// ---------------- K_prep: BN-normalize (inline finalize) + build waug -------
// waug layout: waug[i*COLS + j*256 + rh]
__global__ __launch_bounds__(256) void k_prep(const float* __restrict__ Ps,
                                              const float* __restrict__ Pd,
                                              const float* __restrict__ bn_raw,
                                              const float* __restrict__ gs,
                                              const float* __restrict__ bes,
                                              const float* __restrict__ gd,
                                              const float* __restrict__ bed,
                                              const float* __restrict__ ntlw,
                                              const float* __restrict__ ntlv,
                                              const float* __restrict__ ntlb,
                                              float* __restrict__ hsaug,
                                              float* __restrict__ htaug,
                                              float* __restrict__ waug) {
    int blk = blockIdx.x;
    int t   = threadIdx.x;
    constexpr float invE = 1.f / (float)E_;
    if (blk < 576) {                     // 2048*2*36 / 256
        int gid = blk * 256 + t;
        int m = gid / (2 * STRD), s2 = gid % (2 * STRD);
        if (s2 < STRD) {
            int i = s2;
            float val = 0.f;
            if (i < 32) {
                float mu  = bn_raw[i] * invE;
                float isd = rsqrtf(bn_raw[32 + i] * invE - mu * mu + 1e-5f);
                val = gs[i] * (Ps[(size_t)m * 32 + i] - mu) * isd + bes[i];
            } else if (i == 32) val = 1.f;
            hsaug[(size_t)m * STRD + i] = val;
        } else {
            int j = s2 - STRD;
            float val = 0.f;
            if (j < 32) {
                float mu  = bn_raw[64 + j] * invE;
                float isd = rsqrtf(bn_raw[96 + j] * invE - mu * mu + 1e-5f);
                val = gd[j] * (Pd[(size_t)m * 32 + j] - mu) * isd + bed[j];
            } else if (j == 32) val = 1.f;
            htaug[(size_t)m * STRD + j] = val;
        }
        return;
    }
    // j-fastest order: coalesced ntlw reads; scattered writes
    int gid = (blk - 576) * 256 + t;
    int i   = gid / COLS;
    int rem = gid - i * COLS;
    int rh  = rem / JA;
    int j   = rem - rh * JA;
    float val;
    if (i < 32) val = (j < 32) ? ntlw[((size_t)rh * 32 + i) * 32 + j] : ntlv[rh * 64 + i];
    else        val = (j < 32) ? ntlv[rh * 64 + 32 + j] : ntlb[rh];
    waug[(size_t)i * COLS + j * 256 + rh] = val;
}

// ---------------- K5b: A[m][j*256+rh] = sum_i hsaug[m,i]*waug[i][j*256+rh] --
__global__ __launch_bounds__(256) void k_agemm(const float* __restrict__ hsaug,
                                               const float* __restrict__ waug,
                                               __hip_bfloat16* __restrict__ A) {
    int mt = blockIdx.x;                   // 64 tiles of 32 m
    int j  = blockIdx.y;                   // 33
    int t  = threadIdx.x;                  // rh
    float w[JA];
#pragma unroll
    for (int i = 0; i < JA; i++) w[i] = waug[(size_t)i * COLS + j * 256 + t];

#pragma unroll 2
    for (int ml = 0; ml < 32; ml++) {
        const float* hr = hsaug + (size_t)(mt * 32 + ml) * STRD;   // uniform -> s_load
        float a0 = 0.f, a1 = 0.f;
#pragma unroll
        for (int i = 0; i < 32; i += 2) {
            a0 += hr[i] * w[i];
            a1 += hr[i + 1] * w[i + 1];
        }
        float acc = a0 + a1 + hr[32] * w[32];
        A[(size_t)(mt * 32 + ml) * COLS + j * 256 + t] = __float2bfloat16(acc);
    }
}

// ---------------- K6: z[n][rh] = A[u] . ht_aug[v]; LN partial stats ---------
DEV void load_ht(float* d, const float* __restrict__ htaug, int vv) {
    const float* hp = htaug + (size_t)vv * STRD;
#pragma unroll
    for (int j = 0; j < JA; j++) d[j] = hp[j];
}
DEV void edge_compute(const float* av, const float* ht, int n, int t,
                      __hip_bfloat16* __restrict__ z, float& s1, float& s2) {
    float a0 = 0.f, a1 = 0.f;
#pragma unroll
    for (int j = 0; j < 32; j += 2) {
        a0 += av[j] * ht[j];
        a1 += av[j + 1] * ht[j + 1];
    }
    float acc = a0 + a1 + av[32] * ht[32];
    z[(size_t)n * 256 + t] = __float2bfloat16(acc);
    s1 += acc; s2 += acc * acc;
}

__global__ __launch_bounds__(256) void k_z(const __hip_bfloat16* __restrict__ A,
                                           const float* __restrict__ htaug,
                                           const int* __restrict__ ustart,
                                           const int2* __restrict__ eonv,
                                           __hip_bfloat16* __restrict__ z,
                                           float* __restrict__ zsum,
                                           float* __restrict__ zsq) {
    int t  = threadIdx.x;
    int uu = blockIdx.x;                   // one distinct source node per block
    float s1 = 0.f, s2 = 0.f;
    float av[JA];
#pragma unroll
    for (int j = 0; j < JA; j++)
        av[j] = __bfloat162float(A[(size_t)uu * COLS + j * 256 + t]);   // coalesced
    int e0 = ustart[uu], e1 = ustart[uu + 1];
    if (e0 < e1) {
        int e = e0;
        int2 q0 = eonv[e];
        int n0 = rfl(q0.x), v0 = rfl(q0.y);
        float ht0[JA]; load_ht(ht0, htaug, v0);
        int n1 = 0; float ht1[JA];
        while (true) {
            if (e + 1 < e1) {
                int2 q = eonv[e + 1];
                n1 = rfl(q.x); int v1 = rfl(q.y);
                load_ht(ht1, htaug, v1);
            }
            edge_compute(av, ht0, n0, t, z, s1, s2);
            if (++e >= e1) break;
            if (e + 1 < e1) {
                int2 q = eonv[e + 1];
                n0 = rfl(q.x); int v0b = rfl(q.y);
                load_ht(ht0, htaug, v0b);
            }
            edge_compute(av, ht1, n1, t, z, s1, s2);
            if (++e >= e1) break;
        }
    }
    atomicAdd(&zsum[t], s1);
    atomicAdd(&zsq[t], s2);
}

// ---------------- K8: LN (stats inline) + tanh + contract to logits ---------
__global__ __launch_bounds__(256) void k_logit(const __hip_bfloat16* __restrict__ z,
                                               const float* __restrict__ zsum,
                                               const float* __restrict__ zsq,
                                               const float* __restrict__ ntlu,
                                               const float* __restrict__ ntlg,
                                               const float* __restrict__ ntlbe,
                                               float* __restrict__ out) {
    int t  = threadIdx.x;                 // rh = r*16+h
    int n0 = blockIdx.x * 16;
    float mu  = zsum[t] / (float)E_;
    float var = zsq[t] / (float)E_ - mu * mu;
    float isd = rsqrtf(var + 1e-5f);
    float g   = ntlg[t],  be  = ntlbe[t];
    float uw  = ntlu[t];
    float zv[16];
#pragma unroll
    for (int nl = 0; nl < 16; nl++)
        zv[nl] = __bfloat162float(z[(size_t)(n0 + nl) * 256 + t]);
#pragma unroll 1
    for (int nl = 0; nl < 16; nl++) {
        float zn  = g * (zv[nl] - mu) * isd + be;
        float val = uw * tanh_fast(zn);
        val += __shfl_xor(val, 1);
        val += __shfl_xor(val, 2);
        val += __shfl_xor(val, 4);
        val += __shfl_xor(val, 8);
        if ((t & 15) == 0) out[(size_t)(n0 + nl) * 16 + (t >> 4)] = val;
    }
}

// ============================ host side =====================================
extern "C" void kernel_launch(void* const* d_in, const int* in_sizes, int n_in,
                              void* d_out, int out_size, void* d_ws, size_t ws_size,
                              hipStream_t stream) {
    const int*   seq   = (const int*)d_in[0];
    const int*   p2g   = (const int*)d_in[1];
    const int*   idx   = (const int*)d_in[2];
    const int*   u     = (const int*)d_in[3];
    const int*   v     = (const int*)d_in[4];
    const float* emb   = (const float*)d_in[5];
    const float* wihf  = (const float*)d_in[6];
    const float* whhf  = (const float*)d_in[7];
    const float* bihf  = (const float*)d_in[8];
    const float* bhhf  = (const float*)d_in[9];
    const float* wihb  = (const float*)d_in[10];
    const float* whhb  = (const float*)d_in[11];
    const float* bihb  = (const float*)d_in[12];
    const float* bhhb  = (const float*)d_in[13];
    const float* wsrc  = (const float*)d_in[14];
    const float* bsrc  = (const float*)d_in[15];
    const float* wdst  = (const float*)d_in[16];
    const float* bdst  = (const float*)d_in[17];
    const float* gs    = (const float*)d_in[18];
    const float* bes   = (const float*)d_in[19];
    const float* gd    = (const float*)d_in[20];
    const float* bed   = (const float*)d_in[21];
    const float* ntlw  = (const float*)d_in[22];
    const float* ntlv  = (const float*)d_in[23];
    const float* ntlb  = (const float*)d_in[24];
    const float* ntlu  = (const float*)d_in[25];
    const float* ntlg  = (const float*)d_in[26];
    const float* ntlbe = (const float*)d_in[27];
    float* out = (float*)d_out;

    char* ws = (char*)d_ws;
    size_t off = 0;
    auto take = [&](size_t bytes) -> char* {
        char* p = ws + off;
        off = (off + bytes + 255) & ~(size_t)255;
        return p;
    };
    // zeroed region (contiguous, one memset)
    int*   cnt_u  = (int*)  take(2048 * 4);
    int*   cnt_v  = (int*)  take(2048 * 4);
    float* zsum   = (float*)take(256 * 4);
    float* zsq    = (float*)take(256 * 4);
    float* bn_raw = (float*)take(128 * 4);
    size_t zero_bytes = off;
    // rest
    float* x_grp   = (float*)take((size_t)B_ * G_ * 64 * 4);
    int*   ucursor = (int*)  take(2048 * 4);
    int*   ustart  = (int*)  take(2049 * 4);
    int2*  eonv    = (int2*) take((size_t)E_ * 8);
    float* pre     = (float*)take((size_t)2 * 8192 * 256 * 4);
    float* hgrp    = (float*)take((size_t)B_ * G_ * 128 * 4);
    float* Psrc    = (float*)take((size_t)M_ * 32 * 4);
    float* Pdst    = (float*)take((size_t)M_ * 32 * 4);
    float* hsaug   = (float*)take((size_t)M_ * STRD * 4);
    float* htaug   = (float*)take((size_t)M_ * STRD * 4);
    float* waug    = (float*)take((size_t)JA * COLS * 4);
    __hip_bfloat16* Abuf = (__hip_bfloat16*)take((size_t)M_ * COLS * 2);
    __hip_bfloat16* zbuf = (__hip_bfloat16*)take((size_t)E_ * 256 * 2);
    (void)ws_size; (void)in_sizes; (void)n_in; (void)out_size;

    hipMemsetAsync(d_ws, 0, zero_bytes, stream);

    k_eh<<<320, 256, 0, stream>>>(seq, p2g, emb, u, v, x_grp, cnt_u, cnt_v);
    k_pre<<<513, 256, 0, stream>>>(x_grp, wihf, bihf, bhhf, wihb, bihb, bhhb, pre,
                                   cnt_u, ustart, ucursor);
    k_lstm<<<384, 256, 0, stream>>>(pre, whhf, whhb, hgrp, u, v, ucursor, eonv);
    k_gp<<<M_ / 8, 256, 0, stream>>>(idx, p2g, hgrp, cnt_u, cnt_v,
                                     wsrc, bsrc, wdst, bdst, Psrc, Pdst, bn_raw);
    k_prep<<<576 + 1089, 256, 0, stream>>>(Psrc, Pdst, bn_raw, gs, bes, gd, bed,
                                           ntlw, ntlv, ntlb, hsaug, htaug, waug);
    k_agemm<<<dim3(64, JA), 256, 0, stream>>>(hsaug, waug, Abuf);
    k_z<<<M_, 256, 0, stream>>>(Abuf, htaug, ustart, eonv, zbuf, zsum, zsq);
    k_logit<<<E_ / 16, 256, 0, stream>>>(zbuf, zsum, zsq, ntlu, ntlg, ntlbe, out);
}

// Round 6
// 411.788 us; speedup vs baseline: 1.2087x; 1.0139x over previous
//
#include <hip/hip_runtime.h>
#include <hip/hip_bf16.h>
#include <hip/hip_fp16.h>
#include <cstdint>

// Problem constants
constexpr int B_   = 64;
constexpr int L_   = 512;
constexpr int G_   = 128;
constexpr int E_   = 65536;
constexpr int RH   = 256;    // NREL*NHID
constexpr int M_   = 2048;   // B*N distinct nodes
constexpr int JA   = 33;     // augmented j (32 + const-1 slot)
constexpr int COLS = RH * JA;   // 8448

typedef _Float16 v2h __attribute__((ext_vector_type(2)));

#define DEV static __device__ __forceinline__

DEV float sigm(float x) { return 1.f / (1.f + __expf(-x)); }
DEV float tanh_fast(float x) {
    x = fminf(15.f, fmaxf(-15.f, x));
    float e = __expf(2.f * x);
    return (e - 1.f) / (e + 1.f);
}
DEV int rfl(int x) { return __builtin_amdgcn_readfirstlane(x); }
DEV v2h bch(unsigned int x) { union { unsigned int u; v2h h; } c; c.u = x; return c.h; }

// ---------------- K_eh: embed + edge histograms + waug build ----------------
// blocks 0..63: embed; 64..319: hist; 320..1408: waug
// waug layout: waug[i*COLS + j*256 + rh]
__global__ __launch_bounds__(256) void k_eh(const int* __restrict__ seq,
                                            const int* __restrict__ p2g,
                                            const float* __restrict__ emb,
                                            const int* __restrict__ u,
                                            const int* __restrict__ v,
                                            const float* __restrict__ ntlw,
                                            const float* __restrict__ ntlv,
                                            const float* __restrict__ ntlb,
                                            float* __restrict__ xg,
                                            int* __restrict__ cu, int* __restrict__ cv,
                                            float* __restrict__ waug) {
    int blk = blockIdx.x;
    int t   = threadIdx.x;
    if (blk >= 320) {
        int gid = (blk - 320) * 256 + t;      // i*COLS + j*256 + rh (write-coalesced)
        int i   = gid / COLS;
        int rem = gid - i * COLS;
        int j   = rem >> 8;
        int rh  = rem & 255;
        float val;
        if (i < 32) val = (j < 32) ? ntlw[((size_t)rh * 32 + i) * 32 + j] : ntlv[rh * 64 + i];
        else        val = (j < 32) ? ntlv[rh * 64 + 32 + j] : ntlb[rh];
        waug[gid] = val;
        return;
    }
    if (blk >= 64) {
        int n = (blk - 64) * 256 + t;
        atomicAdd(&cu[u[n]], 1);
        atomicAdd(&cv[v[n]], 1);
        return;
    }
    __shared__ float xgl[G_ * 64];          // 32 KB
    for (int i = t; i < G_ * 64; i += 256) xgl[i] = 0.f;
    __syncthreads();
    int b = blk;
    int d = t & 63, part = t >> 6;
#pragma unroll 8
    for (int l = part; l < L_; l += 4) {
        int s = seq[b * L_ + l];
        int g = p2g[b * L_ + l];
        atomicAdd(&xgl[g * 64 + d], emb[s * 64 + d]);
    }
    __syncthreads();
    for (int i = t; i < G_ * 64; i += 256) xg[(size_t)b * G_ * 64 + i] = xgl[i];
}

// ---------------- K_pre: input-gate GEMM (scalar x broadcast) + scan --------
__global__ __launch_bounds__(256) void k_pre(const float* __restrict__ xg,
                                             const float* __restrict__ wihf,
                                             const float* __restrict__ bihf,
                                             const float* __restrict__ bhhf,
                                             const float* __restrict__ wihb,
                                             const float* __restrict__ bihb,
                                             const float* __restrict__ bhhb,
                                             float* __restrict__ pre,
                                             const int* __restrict__ cu,
                                             int* __restrict__ ustart,
                                             int* __restrict__ ucursor) {
    int blk = blockIdx.x;
    int t   = threadIdx.x;
    if (blk == 512) {
        __shared__ int ps[256];
        int base = t * 8, run = 0;
        int c[8], loc[8];
#pragma unroll
        for (int i = 0; i < 8; i++) c[i] = cu[base + i];
#pragma unroll
        for (int i = 0; i < 8; i++) { loc[i] = run; run += c[i]; }
        ps[t] = run;
        __syncthreads();
        for (int off = 1; off < 256; off <<= 1) {
            int a = (t >= off) ? ps[t - off] : 0;
            __syncthreads();
            ps[t] += a;
            __syncthreads();
        }
        int ex = ps[t] - run;
#pragma unroll
        for (int i = 0; i < 8; i++) { ustart[base + i] = ex + loc[i]; ucursor[base + i] = ex + loc[i]; }
        if (t == 255) ustart[2048] = E_;
        return;
    }
    int dir = blk >> 8;
    const float* wih = dir ? wihb : wihf;
    float bias = dir ? (bihb[t] + bhhb[t]) : (bihf[t] + bhhf[t]);
    int r0 = (blk & 255) * 32;

    float4 wv[16];
#pragma unroll
    for (int c = 0; c < 16; c++) wv[c] = ((const float4*)(wih + t * 64))[c];

#pragma unroll 2
    for (int ml = 0; ml < 32; ml++) {
        const float* xr = xg + (size_t)(r0 + ml) * 64;   // wave-uniform -> s_load
        float acc = bias;
#pragma unroll
        for (int c = 0; c < 16; c++) {
            float x0 = xr[4 * c], x1 = xr[4 * c + 1], x2 = xr[4 * c + 2], x3 = xr[4 * c + 3];
            acc += x0 * wv[c].x + x1 * wv[c].y + x2 * wv[c].z + x3 * wv[c].w;
        }
        pre[((size_t)dir * 8192 + r0 + ml) * 256 + t] = acc;   // gate-major, coalesced
    }
}

// ---------------- K_lstm: as R5 (80us). blocks 128..383: edge sort ----------
__global__ __launch_bounds__(256, 1) void k_lstm(const float* __restrict__ pre,
                                                 const float* __restrict__ whh_f,
                                                 const float* __restrict__ whh_b,
                                                 float* __restrict__ hgrp,
                                                 const int* __restrict__ u,
                                                 const int* __restrict__ v,
                                                 int* __restrict__ ucursor,
                                                 int2* __restrict__ eonv) {
    int blk = blockIdx.x;
    int t   = threadIdx.x;
    if (blk >= 128) {
        int n = (blk - 128) * 256 + t;
        int pos = atomicAdd(&ucursor[u[n]], 1);
        eonv[pos] = make_int2(n, v[n]);
        return;
    }
    __shared__ __align__(16) float plds[64][256];
    __shared__ __align__(16) float hist[64][64];
    __shared__ float gl[2][256];
    int dir = blk >> 6;
    int b   = blk & 63;
    const float* whh = dir ? whh_b : whh_f;
    const float* src = pre + ((size_t)dir * 8192 + (size_t)b * G_) * 256;
    int e = t & 63;
    int q = t >> 6;

    float4 wv[16];
#pragma unroll
    for (int c = 0; c < 16; c++) wv[c] = ((const float4*)(whh + (size_t)t * 64))[c];

    float h = 0.f, creg = 0.f;

    for (int half = 0; half < 2; half++) {
        {
            int base = (dir ^ half) ? 64 : 0;
            const float4* s4 = (const float4*)(src + (size_t)base * 256);
            float4* d4 = (float4*)&plds[0][0];
#pragma unroll
            for (int i = 0; i < 16; i++) d4[i * 256 + t] = s4[i * 256 + t];
        }
        __syncthreads();
        for (int kk = 0; kk < 64; kk++) {
            int k = half * 64 + kk;
            int srow = dir ? (63 - kk) : kk;
            float p = plds[srow][t];
            float a0 = p, a1 = 0.f, a2 = 0.f, a3 = 0.f;
#pragma unroll
            for (int c = 0; c < 16; c++) {
                float f0 = __int_as_float(__builtin_amdgcn_readlane(__float_as_int(h), 4 * c + 0));
                float f1 = __int_as_float(__builtin_amdgcn_readlane(__float_as_int(h), 4 * c + 1));
                float f2 = __int_as_float(__builtin_amdgcn_readlane(__float_as_int(h), 4 * c + 2));
                float f3 = __int_as_float(__builtin_amdgcn_readlane(__float_as_int(h), 4 * c + 3));
                a0 += wv[c].x * f0;
                a1 += wv[c].y * f1;
                a2 += wv[c].z * f2;
                a3 += wv[c].w * f3;
            }
            float g = (a0 + a1) + (a2 + a3);
            gl[k & 1][t] = (q == 2) ? tanh_fast(g) : sigm(g);
            __syncthreads();
            float ai = gl[k & 1][e];
            float af = gl[k & 1][64 + e];
            float ag = gl[k & 1][128 + e];
            float ao = gl[k & 1][192 + e];
            creg = af * creg + ai * ag;
            h = ao * tanh_fast(creg);
            if (q == 0) hist[srow][e] = h;
        }
        __syncthreads();
        int sbase = (dir ? (1 - half) : half) * 64;
#pragma unroll
        for (int i = 0; i < 16; i++) {
            int row = q * 16 + i;
            int s = sbase + row;
            hgrp[((size_t)(b * G_ + s)) * 128 + dir * 64 + e] = hist[row][e];
        }
    }
}

// ---------------- K_gp: gather + projections + BN partial stats (fused) -----
__global__ __launch_bounds__(256) void k_gp(const int* __restrict__ idx,
                                            const int* __restrict__ p2g,
                                            const float* __restrict__ hgrp,
                                            const int* __restrict__ cu,
                                            const int* __restrict__ cv,
                                            const float* __restrict__ wsrc,
                                            const float* __restrict__ bsrc,
                                            const float* __restrict__ wdst,
                                            const float* __restrict__ bdst,
                                            float* __restrict__ Ps, float* __restrict__ Pd,
                                            float* __restrict__ bn_raw) {
    __shared__ __align__(16) float hsl[8][128];
    __shared__ float red[256];
    int m0 = blockIdx.x * 8;
    int t  = threadIdx.x;
    int d = t & 127, mh = t >> 7;
#pragma unroll
    for (int rep = 0; rep < 4; rep++) {
        int ml = rep * 2 + mh;
        int m  = m0 + ml;
        int b  = m >> 5;
        float acc = 0.f;
#pragma unroll
        for (int k = 0; k < 8; k++) {
            int l = idx[m * 8 + k];
            int g = p2g[b * L_ + l];
            acc += hgrp[((size_t)b * G_ + g) * 128 + d];
        }
        hsl[ml][d] = acc;
    }
    __syncthreads();
    int ml = t >> 5, o = t & 31;
    int m  = m0 + ml;
    const float4* hp = (const float4*)&hsl[ml][0];
    float cw_u = (float)cu[m], cw_v = (float)cv[m];
#pragma unroll 1
    for (int side = 0; side < 2; side++) {
        const float* W = side ? wdst : wsrc;
        float4 wr[32];
#pragma unroll
        for (int c = 0; c < 32; c++) wr[c] = ((const float4*)(W + (size_t)o * 128))[c];
        float acc = side ? bdst[o] : bsrc[o];
#pragma unroll
        for (int c = 0; c < 32; c++) {
            float4 h4 = hp[c];
            acc += h4.x * wr[c].x + h4.y * wr[c].y + h4.z * wr[c].z + h4.w * wr[c].w;
        }
        (side ? Pd : Ps)[(size_t)m * 32 + o] = acc;
        float cw = side ? cw_v : cw_u;
        red[t] = cw * acc;
        __syncthreads();
        if (t < 32) {
            float s = 0.f;
#pragma unroll
            for (int i = 0; i < 8; i++) s += red[i * 32 + t];
            atomicAdd(&bn_raw[side * 64 + t], s);
        }
        __syncthreads();
        red[t] = cw * acc * acc;
        __syncthreads();
        if (t < 32) {
            float s = 0.f;
#pragma unroll
            for (int i = 0; i < 8; i++) s += red[i * 32 + t];
            atomicAdd(&bn_raw[side * 64 + 32 + t], s);
        }
        __syncthreads();
    }
}

// ---------------- K_prep: BN-normalize; build hsaugT[i][m] and htp (f16x2) --
// blocks 0..263: hsaugT (33*2048, coalesced over m); 264..391: htp (2048*16)
__global__ __launch_bounds__(256) void k_prep(const float* __restrict__ Ps,
                                              const float* __restrict__ Pd,
                                              const float* __restrict__ bn_raw,
                                              const float* __restrict__ gs,
                                              const float* __restrict__ bes,
                                              const float* __restrict__ gd,
                                              const float* __restrict__ bed,
                                              float* __restrict__ hsaugT,
                                              v2h* __restrict__ htp) {
    int blk = blockIdx.x;
    int t   = threadIdx.x;
    constexpr float invE = 1.f / (float)E_;
    if (blk < 264) {                        // 264*256 = 33*2048
        int gid = blk * 256 + t;
        int c = gid >> 11;                   // 0..32
        int m = gid & 2047;
        float val = 1.f;
        if (c < 32) {
            float mu  = bn_raw[c] * invE;
            float isd = rsqrtf(bn_raw[32 + c] * invE - mu * mu + 1e-5f);
            val = gs[c] * (Ps[(size_t)m * 32 + c] - mu) * isd + bes[c];
        }
        hsaugT[(size_t)c * 2048 + m] = val;   // coalesced over m
        return;
    }
    int gid = (blk - 264) * 256 + t;         // 128*256 = 2048*16
    int m  = gid >> 4;
    int jp = gid & 15;
    int j0 = 2 * jp, j1 = 2 * jp + 1;
    float mu0  = bn_raw[64 + j0] * invE;
    float isd0 = rsqrtf(bn_raw[96 + j0] * invE - mu0 * mu0 + 1e-5f);
    float mu1  = bn_raw[64 + j1] * invE;
    float isd1 = rsqrtf(bn_raw[96 + j1] * invE - mu1 * mu1 + 1e-5f);
    float h0 = gd[j0] * (Pd[(size_t)m * 32 + j0] - mu0) * isd0 + bed[j0];
    float h1 = gd[j1] * (Pd[(size_t)m * 32 + j1] - mu1) * isd1 + bed[j1];
    v2h p;
    p.x = (_Float16)h0; p.y = (_Float16)h1;
    htp[gid] = p;                            // coalesced
}

// ---------------- K_agemm: A pairs (f16x2) + A32 bias plane -----------------
// jp<16: Ah[m][jp*256+rh] = (A[m][2jp][rh], A[m][2jp+1][rh]);  jp==16: A32[m][rh]
__global__ __launch_bounds__(256) void k_agemm(const float* __restrict__ hsaugT,
                                               const float* __restrict__ waug,
                                               v2h* __restrict__ Ah,
                                               float* __restrict__ A32) {
    int mt = blockIdx.x;                   // 64 tiles of 32 m
    int jp = blockIdx.y;                   // 0..16
    int t  = threadIdx.x;                  // rh
    if (jp < 16) {
        float w0[JA], w1[JA];
#pragma unroll
        for (int i = 0; i < JA; i++) {
            w0[i] = waug[(size_t)i * COLS + (2 * jp) * 256 + t];
            w1[i] = waug[(size_t)i * COLS + (2 * jp + 1) * 256 + t];
        }
        float acc0[32], acc1[32];
#pragma unroll
        for (int ml = 0; ml < 32; ml++) { acc0[ml] = 0.f; acc1[ml] = 0.f; }
#pragma unroll 3
        for (int i = 0; i < JA; i++) {
            const float* hr = hsaugT + (size_t)i * 2048 + mt * 32;   // batched s_load x32
#pragma unroll
            for (int ml = 0; ml < 32; ml++) {
                acc0[ml] += hr[ml] * w0[i];
                acc1[ml] += hr[ml] * w1[i];
            }
        }
#pragma unroll
        for (int ml = 0; ml < 32; ml++) {
            v2h p;
            p.x = (_Float16)acc0[ml]; p.y = (_Float16)acc1[ml];
            Ah[(size_t)(mt * 32 + ml) * 4096 + jp * 256 + t] = p;
        }
    } else {
        float w2[JA];
#pragma unroll
        for (int i = 0; i < JA; i++) w2[i] = waug[(size_t)i * COLS + 32 * 256 + t];
        float acc[32];
#pragma unroll
        for (int ml = 0; ml < 32; ml++) acc[ml] = 0.f;
#pragma unroll 3
        for (int i = 0; i < JA; i++) {
            const float* hr = hsaugT + (size_t)i * 2048 + mt * 32;
#pragma unroll
            for (int ml = 0; ml < 32; ml++) acc[ml] += hr[ml] * w2[i];
        }
#pragma unroll
        for (int ml = 0; ml < 32; ml++)
            A32[(size_t)(mt * 32 + ml) * 256 + t] = acc[ml];
    }
}

// ---------------- K_z: z = A[u].ht[v] via v_dot2_f32_f16; LN partials -------
DEV void load_htp(unsigned int* d, const unsigned int* __restrict__ htp, int vv) {
    const unsigned int* hp = htp + vv * 16;   // uniform -> 2x s_load_dwordx8
#pragma unroll
    for (int i = 0; i < 16; i++) d[i] = hp[i];
}
DEV void edge_fd(const unsigned int* av, const unsigned int* ht, float av32,
                 int n, int t, _Float16* __restrict__ zh, float& s1, float& s2) {
    float acc = av32;
#pragma unroll
    for (int jp = 0; jp < 16; jp++)
        acc = __builtin_amdgcn_fdot2(bch(av[jp]), bch(ht[jp]), acc, false);
    zh[(size_t)n * 256 + t] = (_Float16)acc;
    s1 += acc; s2 += acc * acc;
}

__global__ __launch_bounds__(256) void k_z(const unsigned int* __restrict__ Ah,
                                           const float* __restrict__ A32,
                                           const unsigned int* __restrict__ htp,
                                           const int* __restrict__ ustart,
                                           const int2* __restrict__ eonv,
                                           _Float16* __restrict__ zh,
                                           float* __restrict__ zsum,
                                           float* __restrict__ zsq) {
    int t  = threadIdx.x;
    int uu = blockIdx.x;                   // one distinct source node per block
    float s1 = 0.f, s2 = 0.f;
    unsigned int av[16];
#pragma unroll
    for (int jp = 0; jp < 16; jp++)
        av[jp] = Ah[(size_t)uu * 4096 + jp * 256 + t];   // coalesced 4B
    float av32 = A32[(size_t)uu * 256 + t];
    int e0 = ustart[uu], e1 = ustart[uu + 1];
    if (e0 < e1) {
        int e = e0;
        int2 q0 = eonv[e];
        int n0 = rfl(q0.x), v0 = rfl(q0.y);
        unsigned int ht0[16]; load_htp(ht0, htp, v0);
        int n1 = 0; unsigned int ht1[16];
        while (true) {
            if (e + 1 < e1) {
                int2 q = eonv[e + 1];
                n1 = rfl(q.x); int v1 = rfl(q.y);
                load_htp(ht1, htp, v1);
            }
            edge_fd(av, ht0, av32, n0, t, zh, s1, s2);
            if (++e >= e1) break;
            if (e + 1 < e1) {
                int2 q = eonv[e + 1];
                n0 = rfl(q.x); int v0b = rfl(q.y);
                load_htp(ht0, htp, v0b);
            }
            edge_fd(av, ht1, av32, n1, t, zh, s1, s2);
            if (++e >= e1) break;
        }
    }
    atomicAdd(&zsum[t], s1);
    atomicAdd(&zsq[t], s2);
}

// ---------------- K_logit: LN (stats inline) + tanh + contract --------------
__global__ __launch_bounds__(256) void k_logit(const _Float16* __restrict__ zh,
                                               const float* __restrict__ zsum,
                                               const float* __restrict__ zsq,
                                               const float* __restrict__ ntlu,
                                               const float* __restrict__ ntlg,
                                               const float* __restrict__ ntlbe,
                                               float* __restrict__ out) {
    int t  = threadIdx.x;                 // rh = r*16+h
    int n0 = blockIdx.x * 16;
    float mu  = zsum[t] / (float)E_;
    float var = zsq[t] / (float)E_ - mu * mu;
    float isd = rsqrtf(var + 1e-5f);
    float g   = ntlg[t],  be  = ntlbe[t];
    float uw  = ntlu[t];
    float zv[16];
#pragma unroll
    for (int nl = 0; nl < 16; nl++)
        zv[nl] = (float)zh[(size_t)(n0 + nl) * 256 + t];
#pragma unroll 1
    for (int nl = 0; nl < 16; nl++) {
        float zn  = g * (zv[nl] - mu) * isd + be;
        float val = uw * tanh_fast(zn);
        val += __shfl_xor(val, 1);
        val += __shfl_xor(val, 2);
        val += __shfl_xor(val, 4);
        val += __shfl_xor(val, 8);
        if ((t & 15) == 0) out[(size_t)(n0 + nl) * 16 + (t >> 4)] = val;
    }
}

// ============================ host side =====================================
extern "C" void kernel_launch(void* const* d_in, const int* in_sizes, int n_in,
                              void* d_out, int out_size, void* d_ws, size_t ws_size,
                              hipStream_t stream) {
    const int*   seq   = (const int*)d_in[0];
    const int*   p2g   = (const int*)d_in[1];
    const int*   idx   = (const int*)d_in[2];
    const int*   u     = (const int*)d_in[3];
    const int*   v     = (const int*)d_in[4];
    const float* emb   = (const float*)d_in[5];
    const float* wihf  = (const float*)d_in[6];
    const float* whhf  = (const float*)d_in[7];
    const float* bihf  = (const float*)d_in[8];
    const float* bhhf  = (const float*)d_in[9];
    const float* wihb  = (const float*)d_in[10];
    const float* whhb  = (const float*)d_in[11];
    const float* bihb  = (const float*)d_in[12];
    const float* bhhb  = (const float*)d_in[13];
    const float* wsrc  = (const float*)d_in[14];
    const float* bsrc  = (const float*)d_in[15];
    const float* wdst  = (const float*)d_in[16];
    const float* bdst  = (const float*)d_in[17];
    const float* gs    = (const float*)d_in[18];
    const float* bes   = (const float*)d_in[19];
    const float* gd    = (const float*)d_in[20];
    const float* bed   = (const float*)d_in[21];
    const float* ntlw  = (const float*)d_in[22];
    const float* ntlv  = (const float*)d_in[23];
    const float* ntlb  = (const float*)d_in[24];
    const float* ntlu  = (const float*)d_in[25];
    const float* ntlg  = (const float*)d_in[26];
    const float* ntlbe = (const float*)d_in[27];
    float* out = (float*)d_out;

    char* ws = (char*)d_ws;
    size_t off = 0;
    auto take = [&](size_t bytes) -> char* {
        char* p = ws + off;
        off = (off + bytes + 255) & ~(size_t)255;
        return p;
    };
    // zeroed region (contiguous, one memset)
    int*   cnt_u  = (int*)  take(2048 * 4);
    int*   cnt_v  = (int*)  take(2048 * 4);
    float* zsum   = (float*)take(256 * 4);
    float* zsq    = (float*)take(256 * 4);
    float* bn_raw = (float*)take(128 * 4);
    size_t zero_bytes = off;
    // rest
    float* x_grp   = (float*)take((size_t)B_ * G_ * 64 * 4);
    int*   ucursor = (int*)  take(2048 * 4);
    int*   ustart  = (int*)  take(2049 * 4);
    int2*  eonv    = (int2*) take((size_t)E_ * 8);
    float* pre     = (float*)take((size_t)2 * 8192 * 256 * 4);
    float* hgrp    = (float*)take((size_t)B_ * G_ * 128 * 4);
    float* Psrc    = (float*)take((size_t)M_ * 32 * 4);
    float* Pdst    = (float*)take((size_t)M_ * 32 * 4);
    float* hsaugT  = (float*)take((size_t)36 * 2048 * 4);
    v2h*   htp     = (v2h*)  take((size_t)M_ * 16 * 4);
    float* waug    = (float*)take((size_t)JA * COLS * 4);
    v2h*   Ah      = (v2h*)  take((size_t)M_ * 4096 * 4);
    float* A32     = (float*)take((size_t)M_ * 256 * 4);
    _Float16* zbuf = (_Float16*)take((size_t)E_ * 256 * 2);
    (void)ws_size; (void)in_sizes; (void)n_in; (void)out_size;

    hipMemsetAsync(d_ws, 0, zero_bytes, stream);

    k_eh<<<320 + 1089, 256, 0, stream>>>(seq, p2g, emb, u, v, ntlw, ntlv, ntlb,
                                         x_grp, cnt_u, cnt_v, waug);
    k_pre<<<513, 256, 0, stream>>>(x_grp, wihf, bihf, bhhf, wihb, bihb, bhhb, pre,
                                   cnt_u, ustart, ucursor);
    k_lstm<<<384, 256, 0, stream>>>(pre, whhf, whhb, hgrp, u, v, ucursor, eonv);
    k_gp<<<M_ / 8, 256, 0, stream>>>(idx, p2g, hgrp, cnt_u, cnt_v,
                                     wsrc, bsrc, wdst, bdst, Psrc, Pdst, bn_raw);
    k_prep<<<392, 256, 0, stream>>>(Psrc, Pdst, bn_raw, gs, bes, gd, bed, hsaugT, htp);
    k_agemm<<<dim3(64, 17), 256, 0, stream>>>(hsaugT, waug, Ah, A32);
    k_z<<<M_, 256, 0, stream>>>((const unsigned int*)Ah, A32, (const unsigned int*)htp,
                                ustart, eonv, zbuf, zsum, zsq);
    k_logit<<<E_ / 16, 256, 0, stream>>>(zbuf, zsum, zsq, ntlu, ntlg, ntlbe, out);
}